// Round 4
// baseline (842.896 us; speedup 1.0000x reference)
//
#include <hip/hip_runtime.h>
#include <math.h>

#define NPIX 16384

typedef __bf16 bf16x8 __attribute__((ext_vector_type(8)));
typedef float f32x4 __attribute__((ext_vector_type(4)));
typedef unsigned short u16;
typedef unsigned int u32;

__device__ __forceinline__ u16 f2bf(float f) {
    u32 u = __float_as_uint(f);
    u32 r = (u + 0x7FFFu + ((u >> 16) & 1u)) >> 16;
    return (u16)r;
}
__device__ __forceinline__ float bf2f(u32 s) { return __uint_as_float(s << 16); }
__device__ __forceinline__ u32 pk2(float a, float b) {
    return (u32)f2bf(a) | ((u32)f2bf(b) << 16);
}

// ---------------- K0w: convert weights to bf16 ----------------
__global__ __launch_bounds__(256) void k_cvtw(
    const float* __restrict__ wq, const float* __restrict__ wpw,
    const float* __restrict__ wout,
    u16* __restrict__ wq_b, u16* __restrict__ wpw_b, u16* __restrict__ wout_b)
{
    int id = (blockIdx.x * 256 + threadIdx.x) * 4;
    const float* s; u16* d; int off;
    if (id < 131072)      { s = wq;   d = wq_b;   off = id; }
    else if (id < 393216) { s = wpw;  d = wpw_b;  off = id - 131072; }
    else                  { s = wout; d = wout_b; off = id - 393216; }
    f32x4 v = *(const f32x4*)(s + off);
    uint2 u; u.x = pk2(v[0], v[1]); u.y = pk2(v[2], v[3]);
    *(uint2*)(d + off) = u;
}

// ---------------- K0: depthwise 3x3 conv + transpose to [n][c] bf16 ----------------
__global__ __launch_bounds__(256) void k_conv(
    const float* __restrict__ fmap, const float* __restrict__ wdw,
    u16* __restrict__ fmapT, u16* __restrict__ dwT)
{
    const int t = threadIdx.x;
    const int lane = t & 63, w = t >> 6;
    const int x = blockIdx.x, b = blockIdx.y;

    __shared__ u16 dst[2][128][66];   // 33,792 B -> 4 blocks/CU

    const float mLf = (lane == 0) ? 0.f : 1.f;
    const float mRf = (lane == 63) ? 0.f : 1.f;
    const float mTf = (x > 0) ? 1.f : 0.f;
    const float mBf = (x < 127) ? 1.f : 0.f;
    const int dT = (x > 0) ? -128 : 0;
    const int dB = (x < 127) ? 128 : 0;

    const size_t nbase = (size_t)b * NPIX + (size_t)x * 128;

    for (int chunk = 0; chunk < 4; ++chunk) {
        for (int g = 0; g < 4; ++g) {
            const int cl0 = w * 16 + g * 4;      // channel within chunk
            const int c0 = chunk * 64 + cl0;     // global channel
            float2 T[4], M[4], B[4];
            #pragma unroll
            for (int i = 0; i < 4; ++i) {
                const float* p = fmap + ((size_t)(b * 256 + c0 + i)) * NPIX + (size_t)x * 128;
                M[i] = ((const float2*)p)[lane];
                T[i] = ((const float2*)(p + dT))[lane];
                B[i] = ((const float2*)(p + dB))[lane];
            }
            #pragma unroll
            for (int i = 0; i < 4; ++i) {
                const float* wc = wdw + (c0 + i) * 9;  // block-uniform -> scalar loads
                float w0 = wc[0] * mTf, w1 = wc[1] * mTf, w2 = wc[2] * mTf;
                float w3 = wc[3],       w4 = wc[4],       w5 = wc[5];
                float w6 = wc[6] * mBf, w7 = wc[7] * mBf, w8 = wc[8] * mBf;
                float tL = __shfl_up(T[i].y, 1) * mLf;
                float mL_ = __shfl_up(M[i].y, 1) * mLf;
                float bL = __shfl_up(B[i].y, 1) * mLf;
                float tR = __shfl_down(T[i].x, 1) * mRf;
                float mR_ = __shfl_down(M[i].x, 1) * mRf;
                float bR = __shfl_down(B[i].x, 1) * mRf;
                float o0 = w0 * tL     + w1 * T[i].x + w2 * T[i].y
                         + w3 * mL_    + w4 * M[i].x + w5 * M[i].y
                         + w6 * bL     + w7 * B[i].x + w8 * B[i].y;
                float o1 = w0 * T[i].x + w1 * T[i].y + w2 * tR
                         + w3 * M[i].x + w4 * M[i].y + w5 * mR_
                         + w6 * B[i].x + w7 * B[i].y + w8 * bR;
                int cl = cl0 + i;
                dst[0][2 * lane][cl]     = f2bf(M[i].x);
                dst[0][2 * lane + 1][cl] = f2bf(M[i].y);
                dst[1][2 * lane][cl]     = f2bf(o0);
                dst[1][2 * lane + 1][cl] = f2bf(o1);
            }
        }
        __syncthreads();
        #pragma unroll
        for (int T2 = 0; T2 < 2; ++T2) {
            u16* gp = T2 ? dwT : fmapT;
            #pragma unroll
            for (int it = 0; it < 4; ++it) {
                int u = it * 256 + t;
                int y = u >> 3, c8 = (u & 7) * 8;
                const u16* s = &dst[T2][y][c8];
                uint4 val;
                val.x = *(const u32*)(s);
                val.y = *(const u32*)(s + 2);
                val.z = *(const u32*)(s + 4);
                val.w = *(const u32*)(s + 6);
                *(uint4*)(gp + (nbase + y) * 256 + chunk * 64 + c8) = val;
            }
        }
        __syncthreads();
    }
}

// ---------------- K2+K3 fused: kv projection + exp + context + denom ----------------
__global__ __launch_bounds__(256, 2) void k_kvctx(
    const u16* __restrict__ dwT, const u16* __restrict__ wpw,
    float* __restrict__ ctx, float* __restrict__ denom)
{
    const int t = threadIdx.x;
    const int lane = t & 63, w = t >> 6;
    const int l15 = lane & 15, quad = lane >> 4;

    // XCD-chunked swizzle (1024 blocks, 8 XCDs -> 128-block contiguous chunks)
    const int L = blockIdx.x;
    const int work = (L & 7) * 128 + (L >> 3);
    const int s = work >> 6;          // slice 0..15
    const int b = (work >> 3) & 7;    // batch
    const int h = work & 7;           // head
    const int bh = b * 8 + h;

    __shared__ __align__(16) u16 sm[32768];  // 64 KB
    // regions (u16 offsets): A0=0, A1=8192, B0=16384, B1=24576
    u16* EL = sm;          // [64 ch][128 px] swizzled, aliases A0
    u16* VL = sm + 8192;   // aliases A1

    const int ph = (w & 1) * 64;      // pixel half owned by this wave (GEMM)
    const int ck = (w >> 1);          // 0 = k-channels half, 1 = v-channels half

    const int srow = t >> 3;          // staging row 0..31 (+32p)
    const int sg = t & 7;             // staging granule

    f32x4 ctxacc[4] = {};
    float dpart[4] = {0.f, 0.f, 0.f, 0.f};

    uint4 ra[4], rb[4];

#define KV_STAGE_LOAD(stv, kcv)                                                        \
    {                                                                                  \
        const u16* xr = dwT + ((size_t)b * NPIX + s * 1024 + (stv) * 128) * 256;       \
        _Pragma("unroll")                                                              \
        for (int p = 0; p < 4; ++p) {                                                  \
            int row = srow + 32 * p;                                                   \
            int wr = (row < 64) ? (h * 64 + row) : (512 + h * 64 + (row - 64));        \
            ra[p] = *(const uint4*)(wpw + (size_t)wr * 256 + (kcv) * 64 + sg * 8);     \
            rb[p] = *(const uint4*)(xr + (size_t)row * 256 + (kcv) * 64 + sg * 8);     \
        }                                                                              \
    }

#define KV_STAGE_WRITE(bufi)                                                           \
    {                                                                                  \
        u16* Ad = sm + (bufi) * 8192;                                                  \
        u16* Bd = sm + 16384 + (bufi) * 8192;                                          \
        _Pragma("unroll")                                                              \
        for (int p = 0; p < 4; ++p) {                                                  \
            int row = srow + 32 * p;                                                   \
            int off = row * 64 + ((sg ^ (row & 7)) << 3);                              \
            *(uint4*)(Ad + off) = ra[p];                                               \
            *(uint4*)(Bd + off) = rb[p];                                               \
        }                                                                              \
    }

    KV_STAGE_LOAD(0, 0);   // prologue: st=0, kc=0

    for (int st = 0; st < 8; ++st) {
        KV_STAGE_WRITE(0);
        __syncthreads();
        f32x4 acc[4][4] = {};
        #pragma unroll
        for (int kc = 0; kc < 4; ++kc) {
            if (kc < 3) KV_STAGE_LOAD(st, kc + 1);
            {
                const u16* Ax = sm + (kc & 1) * 8192;
                const u16* Bx = sm + 16384 + (kc & 1) * 8192;
                #pragma unroll
                for (int kk = 0; kk < 64; kk += 32) {
                    bf16x8 av[4], bv[4];
                    #pragma unroll
                    for (int mf = 0; mf < 4; ++mf) {
                        int pr = ph + mf * 16 + l15;
                        int pg = ((kk >> 3) + quad) ^ (pr & 7);
                        av[mf] = *(const bf16x8*)(Bx + pr * 64 + (pg << 3));
                    }
                    #pragma unroll
                    for (int nf = 0; nf < 4; ++nf) {
                        int wr2 = ck * 64 + nf * 16 + l15;
                        int wg = ((kk >> 3) + quad) ^ (wr2 & 7);
                        bv[nf] = *(const bf16x8*)(Ax + wr2 * 64 + (wg << 3));
                    }
                    #pragma unroll
                    for (int mf = 0; mf < 4; ++mf)
                        #pragma unroll
                        for (int nf = 0; nf < 4; ++nf)
                            acc[mf][nf] = __builtin_amdgcn_mfma_f32_16x16x32_bf16(av[mf], bv[nf], acc[mf][nf], 0, 0, 0);
                }
            }
            if (kc < 3) {
                KV_STAGE_WRITE((kc + 1) & 1);
                __syncthreads();
            }
        }
        __syncthreads();   // all GEMM reads done before EL/VL (A0/A1) overwrite
        // epilogue: acc rows = pixels, cols = channels; write 4 px / 8B, swizzled.
        u16* dst = ck ? VL : EL;
        #pragma unroll
        for (int nf = 0; nf < 4; ++nf) {
            const int ch = nf * 16 + l15;
            const int key = ch & 7;
            float colsum = 0.f;
            #pragma unroll
            for (int mf = 0; mf < 4; ++mf) {
                const int c = ph + mf * 16 + quad * 4;
                float v0 = acc[mf][nf][0], v1 = acc[mf][nf][1];
                float v2 = acc[mf][nf][2], v3 = acc[mf][nf][3];
                if (ck == 0) {
                    v0 = __expf(v0); v1 = __expf(v1);
                    v2 = __expf(v2); v3 = __expf(v3);
                    colsum += (v0 + v1) + (v2 + v3);
                }
                uint2 u; u.x = pk2(v0, v1); u.y = pk2(v2, v3);
                int addr = ch * 128 + ((((c >> 3) ^ key)) << 3) + (c & 7);
                *(uint2*)(dst + addr) = u;
            }
            if (ck == 0) {
                colsum += __shfl_xor(colsum, 16);
                colsum += __shfl_xor(colsum, 32);
                dpart[nf] += colsum;
            }
        }
        if (st < 7) KV_STAGE_LOAD(st + 1, 0);   // prefetch next subtile (overlaps ctx)
        __syncthreads();
        // ctx accumulation: wave w owns e-rows [w*16, w*16+16)
        #pragma unroll
        for (int kk2 = 0; kk2 < 128; kk2 += 32) {
            int ar = w * 16 + l15;
            int ag = ((kk2 >> 3) + quad) ^ (ar & 7);
            bf16x8 av = *(const bf16x8*)(VL + ar * 128 + (ag << 3));
            #pragma unroll
            for (int nf = 0; nf < 4; ++nf) {
                int br = nf * 16 + l15;
                int bg = ((kk2 >> 3) + quad) ^ (br & 7);
                bf16x8 bv = *(const bf16x8*)(EL + br * 128 + (bg << 3));
                ctxacc[nf] = __builtin_amdgcn_mfma_f32_16x16x32_bf16(av, bv, ctxacc[nf], 0, 0, 0);
            }
        }
        __syncthreads();   // ctx reads done before next subtile's staging write
    }
    // finale: one atomic pass
    #pragma unroll
    for (int nf = 0; nf < 4; ++nf)
        #pragma unroll
        for (int r = 0; r < 4; ++r) {
            int e = w * 16 + quad * 4 + r;
            int d = nf * 16 + l15;
            atomicAdd(ctx + ((size_t)bh * 64 + e) * 64 + d, ctxacc[nf][r]);
        }
    if (ck == 0 && quad == 0) {
        #pragma unroll
        for (int nf = 0; nf < 4; ++nf)
            atomicAdd(denom + bh * 64 + nf * 16 + l15, dpart[nf]);
    }
#undef KV_STAGE_LOAD
#undef KV_STAGE_WRITE
}

// ---------------- K3b: normalize context -> bf16 once ----------------
// ctxn[bh][e][d] = ctx[bh][e][d] / denom[bh][d]
__global__ __launch_bounds__(256) void k_ctxn(
    const float* __restrict__ ctx, const float* __restrict__ denom,
    u16* __restrict__ ctxn)
{
    const int bh = blockIdx.x;
    const int t = threadIdx.x;
    const int e = t >> 2, d0 = (t & 3) * 16;
    const float* cr = ctx + ((size_t)bh * 64 + e) * 64 + d0;
    const float* dr = denom + bh * 64 + d0;
    u16* o = ctxn + ((size_t)bh * 64 + e) * 64 + d0;
    #pragma unroll
    for (int i = 0; i < 4; ++i) {
        f32x4 c = *(const f32x4*)(cr + i * 4);
        f32x4 dv = *(const f32x4*)(dr + i * 4);
        uint2 u;
        u.x = pk2(c[0] / dv[0], c[1] / dv[1]);
        u.y = pk2(c[2] / dv[2], c[3] / dv[3]);
        *(uint2*)(o + i * 4) = u;
    }
}

// ---------------- K1: q projection GEMM + fused per-(pixel,head) softmax * 1/8 ----------------
__global__ __launch_bounds__(256) void k_proj_q(
    const u16* __restrict__ fmapT, const u16* __restrict__ wq,
    u16* __restrict__ q)
{
    const int t = threadIdx.x;
    const int lane = t & 63, w = t >> 6;
    const int l15 = lane & 15, quad = lane >> 4;
    const int n0 = blockIdx.x * 128;
    const int o0 = blockIdx.y * 128;
    const int b  = blockIdx.z;
    __shared__ __align__(16) unsigned char smraw[71680];
    u16* sm16 = (u16*)smraw;   // A0=0, A1=8192, B0=16384, B1=24576 (u16 offsets)
    f32x4 acc[4][4] = {};
    const int mh = (w >> 1) * 64, nh = (w & 1) * 64;
    const u16* wrow = wq + (size_t)o0 * 256;
    const u16* xrow = fmapT + ((size_t)b * NPIX + n0) * 256;
    const int srow = t >> 3;
    const int sg = t & 7;
    uint4 ra[4], rb[4];

#define Q_STAGE_LOAD(kcv)                                                              \
    {                                                                                  \
        _Pragma("unroll")                                                              \
        for (int p = 0; p < 4; ++p) {                                                  \
            int row = srow + 32 * p;                                                   \
            ra[p] = *(const uint4*)(wrow + (size_t)row * 256 + (kcv) * 64 + sg * 8);   \
            rb[p] = *(const uint4*)(xrow + (size_t)row * 256 + (kcv) * 64 + sg * 8);   \
        }                                                                              \
    }

#define Q_STAGE_WRITE(bufi)                                                            \
    {                                                                                  \
        u16* Ad = sm16 + (bufi) * 8192;                                                \
        u16* Bd = sm16 + 16384 + (bufi) * 8192;                                        \
        _Pragma("unroll")                                                              \
        for (int p = 0; p < 4; ++p) {                                                  \
            int row = srow + 32 * p;                                                   \
            int off = row * 64 + ((sg ^ (row & 7)) << 3);                              \
            *(uint4*)(Ad + off) = ra[p];                                               \
            *(uint4*)(Bd + off) = rb[p];                                               \
        }                                                                              \
    }

    Q_STAGE_LOAD(0);
    Q_STAGE_WRITE(0);
    __syncthreads();
    #pragma unroll
    for (int kc = 0; kc < 4; ++kc) {
        if (kc < 3) Q_STAGE_LOAD(kc + 1);
        {
            const u16* Ax = sm16 + (kc & 1) * 8192;
            const u16* Bx = sm16 + 16384 + (kc & 1) * 8192;
            #pragma unroll
            for (int kk = 0; kk < 64; kk += 32) {
                bf16x8 av[4], bv[4];
                #pragma unroll
                for (int mf = 0; mf < 4; ++mf) {
                    int arow = mh + mf * 16 + l15;
                    int agr = ((kk >> 3) + quad) ^ (arow & 7);
                    av[mf] = *(const bf16x8*)(Ax + arow * 64 + (agr << 3));
                }
                #pragma unroll
                for (int nf = 0; nf < 4; ++nf) {
                    int brow = nh + nf * 16 + l15;
                    int bgr = ((kk >> 3) + quad) ^ (brow & 7);
                    bv[nf] = *(const bf16x8*)(Bx + brow * 64 + (bgr << 3));
                }
                #pragma unroll
                for (int mf = 0; mf < 4; ++mf)
                    #pragma unroll
                    for (int nf = 0; nf < 4; ++nf)
                        acc[mf][nf] = __builtin_amdgcn_mfma_f32_16x16x32_bf16(av[mf], bv[nf], acc[mf][nf], 0, 0, 0);
            }
        }
        if (kc < 3) {
            Q_STAGE_WRITE((kc + 1) & 1);
            __syncthreads();
        }
    }
    __syncthreads();
    float* ep = (float*)smraw;  // [128 pix][140] fp32 logits, transposed
    #pragma unroll
    for (int mf = 0; mf < 4; ++mf)
        #pragma unroll
        for (int nf = 0; nf < 4; ++nf)
            #pragma unroll
            for (int r = 0; r < 4; ++r) {
                int row = mh + mf * 16 + quad * 4 + r;  // local channel 0..127
                int col = nh + nf * 16 + l15;           // pixel
                ep[col * 140 + row] = acc[mf][nf][r];
            }
    __syncthreads();
    const int h0 = blockIdx.y * 2;
    for (int p = 0; p < 8; ++p) {
        int unit = p * 32 + (t >> 3);
        int pix = unit >> 1, hh = unit & 1;
        int d8 = (t & 7) * 8;
        f32x4 v0 = *(const f32x4*)(ep + pix * 140 + hh * 64 + d8);
        f32x4 v1 = *(const f32x4*)(ep + pix * 140 + hh * 64 + d8 + 4);
        float e0 = __expf(v0[0]), e1 = __expf(v0[1]), e2 = __expf(v0[2]), e3 = __expf(v0[3]);
        float e4 = __expf(v1[0]), e5 = __expf(v1[1]), e6 = __expf(v1[2]), e7 = __expf(v1[3]);
        float s = ((e0 + e1) + (e2 + e3)) + ((e4 + e5) + (e6 + e7));
        s += __shfl_xor(s, 1); s += __shfl_xor(s, 2); s += __shfl_xor(s, 4);
        float r = 0.125f / s;
        uint4 u;
        u.x = pk2(e0 * r, e1 * r); u.y = pk2(e2 * r, e3 * r);
        u.z = pk2(e4 * r, e5 * r); u.w = pk2(e6 * r, e7 * r);
        size_t off = (((size_t)b * 8 + h0 + hh) * NPIX + n0 + pix) * 64 + d8;
        *(uint4*)(q + off) = u;
    }
#undef Q_STAGE_LOAD
#undef Q_STAGE_WRITE
}

// ---------------- K4: out = (gelu(q @ ctxn^T)) @ w_out^T + b ----------------
// v2: 64-px tiles (2048 blocks), per-head {GEMM1 -> gelu -> G -> GEMM2 accum},
// 3 barriers/head, issue-early prefetch of next head's q/ctxn/wout during GEMM2.
// LDS 64,512 B -> 2 blocks/CU.
__global__ __launch_bounds__(256) void k_attnout(
    const u16* __restrict__ q, const u16* __restrict__ ctxn,
    const u16* __restrict__ wout, const float* __restrict__ bout,
    float* __restrict__ out)
{
    const int t = threadIdx.x;
    const int lane = t & 63, w = t >> 6;
    const int l15 = lane & 15, quad = lane >> 4;
    const int n0 = blockIdx.x * 64;
    const int b  = blockIdx.y;

    __shared__ __align__(16) u16 qs[64 * 72];    // q tile [px][d]
    __shared__ __align__(16) u16 cs[64 * 72];    // ctxn  [e][d]
    __shared__ __align__(16) u16 G [64 * 72];    // gelu  [px][e]
    __shared__ __align__(16) u16 WS[256 * 72];   // wout slice [ch][e]

    uint4 rq[2], rc[2], rw[8];

    auto LOADH = [&](int h) {
        const u16* qb = q + (((size_t)(b * 8 + h)) * NPIX + n0) * 64;
        const u16* cb = ctxn + ((size_t)(b * 8 + h)) * 64 * 64;
        #pragma unroll
        for (int p = 0; p < 2; ++p) {
            int i = p * 256 + t; int row = i >> 3, g = i & 7;
            rq[p] = *(const uint4*)(qb + row * 64 + g * 8);
            rc[p] = *(const uint4*)(cb + row * 64 + g * 8);
        }
        #pragma unroll
        for (int p = 0; p < 8; ++p) {
            int i = p * 256 + t; int row = i >> 3, g = i & 7;
            rw[p] = *(const uint4*)(wout + (size_t)row * 512 + h * 64 + g * 8);
        }
    };
    auto WRITEH = [&]() {
        #pragma unroll
        for (int p = 0; p < 2; ++p) {
            int i = p * 256 + t; int row = i >> 3, g = i & 7;
            *(uint4*)(qs + row * 72 + g * 8) = rq[p];
            *(uint4*)(cs + row * 72 + g * 8) = rc[p];
        }
        #pragma unroll
        for (int p = 0; p < 8; ++p) {
            int i = p * 256 + t; int row = i >> 3, g = i & 7;
            *(uint4*)(WS + row * 72 + g * 8) = rw[p];
        }
    };

    f32x4 acc[4][4] = {};   // out tile: ch = w*64+mf*16, px = nf*16

    LOADH(0);
    WRITEH();
    __syncthreads();

    for (int h = 0; h < 8; ++h) {
        // GEMM1: D[e][px] = sum_d ctxn[e][d] * q[px][d]; wave owns e-rows w*16..+16
        f32x4 a1[4] = {};
        #pragma unroll
        for (int kk = 0; kk < 64; kk += 32) {
            bf16x8 av = *(const bf16x8*)(cs + (w * 16 + l15) * 72 + kk + quad * 8);
            #pragma unroll
            for (int nf = 0; nf < 4; ++nf) {
                bf16x8 bv = *(const bf16x8*)(qs + (nf * 16 + l15) * 72 + kk + quad * 8);
                a1[nf] = __builtin_amdgcn_mfma_f32_16x16x32_bf16(av, bv, a1[nf], 0, 0, 0);
            }
        }
        // gelu -> G[px][e] (4 consecutive e per lane -> one 8B write)
        #pragma unroll
        for (int nf = 0; nf < 4; ++nf) {
            int px = nf * 16 + l15;
            int e0 = w * 16 + quad * 4;
            float x0 = a1[nf][0], x1 = a1[nf][1], x2 = a1[nf][2], x3 = a1[nf][3];
            x0 = 0.5f * x0 * (1.0f + erff(x0 * 0.70710678118654752f));
            x1 = 0.5f * x1 * (1.0f + erff(x1 * 0.70710678118654752f));
            x2 = 0.5f * x2 * (1.0f + erff(x2 * 0.70710678118654752f));
            x3 = 0.5f * x3 * (1.0f + erff(x3 * 0.70710678118654752f));
            uint2 u; u.x = pk2(x0, x1); u.y = pk2(x2, x3);
            *(uint2*)(G + px * 72 + e0) = u;
        }
        __syncthreads();
        if (h < 7) LOADH(h + 1);   // issue-early: latency hides under GEMM2
        // GEMM2: acc[ch][px] += sum_e wout[ch][h*64+e] * G[px][e]
        #pragma unroll
        for (int kk = 0; kk < 64; kk += 32) {
            bf16x8 av2[4], bv2[4];
            #pragma unroll
            for (int mf = 0; mf < 4; ++mf)
                av2[mf] = *(const bf16x8*)(WS + (w * 64 + mf * 16 + l15) * 72 + kk + quad * 8);
            #pragma unroll
            for (int nf = 0; nf < 4; ++nf)
                bv2[nf] = *(const bf16x8*)(G + (nf * 16 + l15) * 72 + kk + quad * 8);
            #pragma unroll
            for (int mf = 0; mf < 4; ++mf)
                #pragma unroll
                for (int nf = 0; nf < 4; ++nf)
                    acc[mf][nf] = __builtin_amdgcn_mfma_f32_16x16x32_bf16(av2[mf], bv2[nf], acc[mf][nf], 0, 0, 0);
        }
        __syncthreads();
        if (h < 7) {
            WRITEH();
            __syncthreads();
        }
    }
    // epilogue
    #pragma unroll
    for (int mf = 0; mf < 4; ++mf)
        #pragma unroll
        for (int nf = 0; nf < 4; ++nf)
            #pragma unroll
            for (int r = 0; r < 4; ++r) {
                int c = w * 64 + mf * 16 + quad * 4 + r;
                int px = nf * 16 + l15;
                out[((size_t)b * 256 + c) * NPIX + n0 + px] = acc[mf][nf][r] + bout[c];
            }
}

extern "C" void kernel_launch(void* const* d_in, const int* in_sizes, int n_in,
                              void* d_out, int out_size, void* d_ws, size_t ws_size,
                              hipStream_t stream)
{
    const float* fmap  = (const float*)d_in[0];
    const float* w_q   = (const float*)d_in[1];
    const float* w_dw  = (const float*)d_in[2];
    const float* w_pw  = (const float*)d_in[3];
    const float* w_out = (const float*)d_in[4];
    const float* b_out = (const float*)d_in[5];
    float* out = (float*)d_out;
    char* ws = (char*)d_ws;

    u16* dwT     = (u16*)(ws);                  // 67,108,864 B  [8][16384][256] (dead after k_kvctx)
    u16* ctxn    = (u16*)(ws);                  // 524,288 B — reuses dwT region post-k_kvctx
    u16* fmapT   = (u16*)(ws + 67108864);       // 67,108,864 B
    u16* q       = (u16*)(ws + 134217728);      // 134,217,728 B
    float* ctx   = (float*)(ws + 402653184);    // 1,048,576 B  [64][64][64]
    float* denom = (float*)(ws + 403701760);    // 16,384 B
    u16* wq_b    = (u16*)(ws + 403718144);      // 262,144 B
    u16* wpw_b   = (u16*)(ws + 403980288);      // 524,288 B
    u16* wout_b  = (u16*)(ws + 404504576);      // 262,144 B
    // total workspace: 404,766,720 B

    hipMemsetAsync(ws + 402653184, 0, 1048576 + 16384, stream);
    k_cvtw<<<512, 256, 0, stream>>>(w_q, w_pw, w_out, wq_b, wpw_b, wout_b);
    k_conv<<<dim3(128, 8), 256, 0, stream>>>(fmap, w_dw, fmapT, dwT);
    k_kvctx<<<1024, 256, 0, stream>>>(dwT, wpw_b, ctx, denom);
    k_ctxn<<<64, 256, 0, stream>>>(ctx, denom, ctxn);   // after k_kvctx; overwrites dwT region
    k_proj_q<<<dim3(128, 4, 8), 256, 0, stream>>>(fmapT, wq_b, q);
    k_attnout<<<dim3(256, 8), 256, 0, stream>>>(q, ctxn, wout_b, b_out, out);
}

// Round 5
// 751.641 us; speedup vs baseline: 1.1214x; 1.1214x over previous
//
#include <hip/hip_runtime.h>
#include <math.h>

#define NPIX 16384

typedef __bf16 bf16x8 __attribute__((ext_vector_type(8)));
typedef float f32x4 __attribute__((ext_vector_type(4)));
typedef unsigned short u16;
typedef unsigned int u32;

__device__ __forceinline__ u16 f2bf(float f) {
    u32 u = __float_as_uint(f);
    u32 r = (u + 0x7FFFu + ((u >> 16) & 1u)) >> 16;
    return (u16)r;
}
__device__ __forceinline__ float bf2f(u32 s) { return __uint_as_float(s << 16); }
__device__ __forceinline__ u32 pk2(float a, float b) {
    return (u32)f2bf(a) | ((u32)f2bf(b) << 16);
}

// ---------------- K0w: convert weights to bf16 ----------------
__global__ __launch_bounds__(256) void k_cvtw(
    const float* __restrict__ wq, const float* __restrict__ wpw,
    const float* __restrict__ wout,
    u16* __restrict__ wq_b, u16* __restrict__ wpw_b, u16* __restrict__ wout_b)
{
    int id = (blockIdx.x * 256 + threadIdx.x) * 4;
    const float* s; u16* d; int off;
    if (id < 131072)      { s = wq;   d = wq_b;   off = id; }
    else if (id < 393216) { s = wpw;  d = wpw_b;  off = id - 131072; }
    else                  { s = wout; d = wout_b; off = id - 393216; }
    f32x4 v = *(const f32x4*)(s + off);
    uint2 u; u.x = pk2(v[0], v[1]); u.y = pk2(v[2], v[3]);
    *(uint2*)(d + off) = u;
}

// ---------------- K0: depthwise 3x3 conv + transpose to [n][c] bf16 ----------------
__global__ __launch_bounds__(256) void k_conv(
    const float* __restrict__ fmap, const float* __restrict__ wdw,
    u16* __restrict__ fmapT, u16* __restrict__ dwT)
{
    const int t = threadIdx.x;
    const int lane = t & 63, w = t >> 6;
    const int x = blockIdx.x, b = blockIdx.y;

    __shared__ u16 dst[2][128][66];   // 33,792 B -> 4 blocks/CU

    const float mLf = (lane == 0) ? 0.f : 1.f;
    const float mRf = (lane == 63) ? 0.f : 1.f;
    const float mTf = (x > 0) ? 1.f : 0.f;
    const float mBf = (x < 127) ? 1.f : 0.f;
    const int dT = (x > 0) ? -128 : 0;
    const int dB = (x < 127) ? 128 : 0;

    const size_t nbase = (size_t)b * NPIX + (size_t)x * 128;

    for (int chunk = 0; chunk < 4; ++chunk) {
        for (int g = 0; g < 4; ++g) {
            const int cl0 = w * 16 + g * 4;      // channel within chunk
            const int c0 = chunk * 64 + cl0;     // global channel
            float2 T[4], M[4], B[4];
            #pragma unroll
            for (int i = 0; i < 4; ++i) {
                const float* p = fmap + ((size_t)(b * 256 + c0 + i)) * NPIX + (size_t)x * 128;
                M[i] = ((const float2*)p)[lane];
                T[i] = ((const float2*)(p + dT))[lane];
                B[i] = ((const float2*)(p + dB))[lane];
            }
            #pragma unroll
            for (int i = 0; i < 4; ++i) {
                const float* wc = wdw + (c0 + i) * 9;  // block-uniform -> scalar loads
                float w0 = wc[0] * mTf, w1 = wc[1] * mTf, w2 = wc[2] * mTf;
                float w3 = wc[3],       w4 = wc[4],       w5 = wc[5];
                float w6 = wc[6] * mBf, w7 = wc[7] * mBf, w8 = wc[8] * mBf;
                float tL = __shfl_up(T[i].y, 1) * mLf;
                float mL_ = __shfl_up(M[i].y, 1) * mLf;
                float bL = __shfl_up(B[i].y, 1) * mLf;
                float tR = __shfl_down(T[i].x, 1) * mRf;
                float mR_ = __shfl_down(M[i].x, 1) * mRf;
                float bR = __shfl_down(B[i].x, 1) * mRf;
                float o0 = w0 * tL     + w1 * T[i].x + w2 * T[i].y
                         + w3 * mL_    + w4 * M[i].x + w5 * M[i].y
                         + w6 * bL     + w7 * B[i].x + w8 * B[i].y;
                float o1 = w0 * T[i].x + w1 * T[i].y + w2 * tR
                         + w3 * M[i].x + w4 * M[i].y + w5 * mR_
                         + w6 * B[i].x + w7 * B[i].y + w8 * bR;
                int cl = cl0 + i;
                dst[0][2 * lane][cl]     = f2bf(M[i].x);
                dst[0][2 * lane + 1][cl] = f2bf(M[i].y);
                dst[1][2 * lane][cl]     = f2bf(o0);
                dst[1][2 * lane + 1][cl] = f2bf(o1);
            }
        }
        __syncthreads();
        #pragma unroll
        for (int T2 = 0; T2 < 2; ++T2) {
            u16* gp = T2 ? dwT : fmapT;
            #pragma unroll
            for (int it = 0; it < 4; ++it) {
                int u = it * 256 + t;
                int y = u >> 3, c8 = (u & 7) * 8;
                const u16* s = &dst[T2][y][c8];
                uint4 val;
                val.x = *(const u32*)(s);
                val.y = *(const u32*)(s + 2);
                val.z = *(const u32*)(s + 4);
                val.w = *(const u32*)(s + 6);
                *(uint4*)(gp + (nbase + y) * 256 + chunk * 64 + c8) = val;
            }
        }
        __syncthreads();
    }
}

// ---------------- K2+K3 fused: kv projection + exp + context + denom ----------------
__global__ __launch_bounds__(256, 2) void k_kvctx(
    const u16* __restrict__ dwT, const u16* __restrict__ wpw,
    float* __restrict__ ctx, float* __restrict__ denom)
{
    const int t = threadIdx.x;
    const int lane = t & 63, w = t >> 6;
    const int l15 = lane & 15, quad = lane >> 4;

    // XCD-chunked swizzle (1024 blocks, 8 XCDs -> 128-block contiguous chunks)
    const int L = blockIdx.x;
    const int work = (L & 7) * 128 + (L >> 3);
    const int s = work >> 6;          // slice 0..15
    const int b = (work >> 3) & 7;    // batch
    const int h = work & 7;           // head
    const int bh = b * 8 + h;

    __shared__ __align__(16) u16 sm[32768];  // 64 KB
    // regions (u16 offsets): A0=0, A1=8192, B0=16384, B1=24576
    u16* EL = sm;          // [64 ch][128 px] swizzled, aliases A0
    u16* VL = sm + 8192;   // aliases A1

    const int ph = (w & 1) * 64;      // pixel half owned by this wave (GEMM)
    const int ck = (w >> 1);          // 0 = k-channels half, 1 = v-channels half

    const int srow = t >> 3;          // staging row 0..31 (+32p)
    const int sg = t & 7;             // staging granule

    f32x4 ctxacc[4] = {};
    float dpart[4] = {0.f, 0.f, 0.f, 0.f};

    uint4 ra[4], rb[4];

#define KV_STAGE_LOAD(stv, kcv)                                                        \
    {                                                                                  \
        const u16* xr = dwT + ((size_t)b * NPIX + s * 1024 + (stv) * 128) * 256;       \
        _Pragma("unroll")                                                              \
        for (int p = 0; p < 4; ++p) {                                                  \
            int row = srow + 32 * p;                                                   \
            int wr = (row < 64) ? (h * 64 + row) : (512 + h * 64 + (row - 64));        \
            ra[p] = *(const uint4*)(wpw + (size_t)wr * 256 + (kcv) * 64 + sg * 8);     \
            rb[p] = *(const uint4*)(xr + (size_t)row * 256 + (kcv) * 64 + sg * 8);     \
        }                                                                              \
    }

#define KV_STAGE_WRITE(bufi)                                                           \
    {                                                                                  \
        u16* Ad = sm + (bufi) * 8192;                                                  \
        u16* Bd = sm + 16384 + (bufi) * 8192;                                          \
        _Pragma("unroll")                                                              \
        for (int p = 0; p < 4; ++p) {                                                  \
            int row = srow + 32 * p;                                                   \
            int off = row * 64 + ((sg ^ (row & 7)) << 3);                              \
            *(uint4*)(Ad + off) = ra[p];                                               \
            *(uint4*)(Bd + off) = rb[p];                                               \
        }                                                                              \
    }

    KV_STAGE_LOAD(0, 0);   // prologue: st=0, kc=0

    for (int st = 0; st < 8; ++st) {
        KV_STAGE_WRITE(0);
        __syncthreads();
        f32x4 acc[4][4] = {};
        #pragma unroll
        for (int kc = 0; kc < 4; ++kc) {
            if (kc < 3) KV_STAGE_LOAD(st, kc + 1);
            {
                const u16* Ax = sm + (kc & 1) * 8192;
                const u16* Bx = sm + 16384 + (kc & 1) * 8192;
                #pragma unroll
                for (int kk = 0; kk < 64; kk += 32) {
                    bf16x8 av[4], bv[4];
                    #pragma unroll
                    for (int mf = 0; mf < 4; ++mf) {
                        int pr = ph + mf * 16 + l15;
                        int pg = ((kk >> 3) + quad) ^ (pr & 7);
                        av[mf] = *(const bf16x8*)(Bx + pr * 64 + (pg << 3));
                    }
                    #pragma unroll
                    for (int nf = 0; nf < 4; ++nf) {
                        int wr2 = ck * 64 + nf * 16 + l15;
                        int wg = ((kk >> 3) + quad) ^ (wr2 & 7);
                        bv[nf] = *(const bf16x8*)(Ax + wr2 * 64 + (wg << 3));
                    }
                    #pragma unroll
                    for (int mf = 0; mf < 4; ++mf)
                        #pragma unroll
                        for (int nf = 0; nf < 4; ++nf)
                            acc[mf][nf] = __builtin_amdgcn_mfma_f32_16x16x32_bf16(av[mf], bv[nf], acc[mf][nf], 0, 0, 0);
                }
            }
            if (kc < 3) {
                KV_STAGE_WRITE((kc + 1) & 1);
                __syncthreads();
            }
        }
        __syncthreads();   // all GEMM reads done before EL/VL (A0/A1) overwrite
        // epilogue: acc rows = pixels, cols = channels; write 4 px / 8B, swizzled.
        u16* dst = ck ? VL : EL;
        #pragma unroll
        for (int nf = 0; nf < 4; ++nf) {
            const int ch = nf * 16 + l15;
            const int key = ch & 7;
            float colsum = 0.f;
            #pragma unroll
            for (int mf = 0; mf < 4; ++mf) {
                const int c = ph + mf * 16 + quad * 4;
                float v0 = acc[mf][nf][0], v1 = acc[mf][nf][1];
                float v2 = acc[mf][nf][2], v3 = acc[mf][nf][3];
                if (ck == 0) {
                    v0 = __expf(v0); v1 = __expf(v1);
                    v2 = __expf(v2); v3 = __expf(v3);
                    colsum += (v0 + v1) + (v2 + v3);
                }
                uint2 u; u.x = pk2(v0, v1); u.y = pk2(v2, v3);
                int addr = ch * 128 + ((((c >> 3) ^ key)) << 3) + (c & 7);
                *(uint2*)(dst + addr) = u;
            }
            if (ck == 0) {
                colsum += __shfl_xor(colsum, 16);
                colsum += __shfl_xor(colsum, 32);
                dpart[nf] += colsum;
            }
        }
        if (st < 7) KV_STAGE_LOAD(st + 1, 0);   // prefetch next subtile (overlaps ctx)
        __syncthreads();
        // ctx accumulation: wave w owns e-rows [w*16, w*16+16)
        #pragma unroll
        for (int kk2 = 0; kk2 < 128; kk2 += 32) {
            int ar = w * 16 + l15;
            int ag = ((kk2 >> 3) + quad) ^ (ar & 7);
            bf16x8 av = *(const bf16x8*)(VL + ar * 128 + (ag << 3));
            #pragma unroll
            for (int nf = 0; nf < 4; ++nf) {
                int br = nf * 16 + l15;
                int bg = ((kk2 >> 3) + quad) ^ (br & 7);
                bf16x8 bv = *(const bf16x8*)(EL + br * 128 + (bg << 3));
                ctxacc[nf] = __builtin_amdgcn_mfma_f32_16x16x32_bf16(av, bv, ctxacc[nf], 0, 0, 0);
            }
        }
        __syncthreads();   // ctx reads done before next subtile's staging write
    }
    // finale: one atomic pass
    #pragma unroll
    for (int nf = 0; nf < 4; ++nf)
        #pragma unroll
        for (int r = 0; r < 4; ++r) {
            int e = w * 16 + quad * 4 + r;
            int d = nf * 16 + l15;
            atomicAdd(ctx + ((size_t)bh * 64 + e) * 64 + d, ctxacc[nf][r]);
        }
    if (ck == 0 && quad == 0) {
        #pragma unroll
        for (int nf = 0; nf < 4; ++nf)
            atomicAdd(denom + bh * 64 + nf * 16 + l15, dpart[nf]);
    }
#undef KV_STAGE_LOAD
#undef KV_STAGE_WRITE
}

// ---------------- K3b: normalize context -> bf16 once ----------------
// ctxn[bh][e][d] = ctx[bh][e][d] / denom[bh][d]
__global__ __launch_bounds__(256) void k_ctxn(
    const float* __restrict__ ctx, const float* __restrict__ denom,
    u16* __restrict__ ctxn)
{
    const int bh = blockIdx.x;
    const int t = threadIdx.x;
    const int e = t >> 2, d0 = (t & 3) * 16;
    const float* cr = ctx + ((size_t)bh * 64 + e) * 64 + d0;
    const float* dr = denom + bh * 64 + d0;
    u16* o = ctxn + ((size_t)bh * 64 + e) * 64 + d0;
    #pragma unroll
    for (int i = 0; i < 4; ++i) {
        f32x4 c = *(const f32x4*)(cr + i * 4);
        f32x4 dv = *(const f32x4*)(dr + i * 4);
        uint2 u;
        u.x = pk2(c[0] / dv[0], c[1] / dv[1]);
        u.y = pk2(c[2] / dv[2], c[3] / dv[3]);
        *(uint2*)(o + i * 4) = u;
    }
}

// ---------------- K1+attn: q projection GEMM + softmax + P@ctxn^T + gelu -> G ----------------
// Extends k_proj_q: after the softmax, each wave (hh = w>>1, px-half = w&1)
// holds P fragments in registers (lane l15 -> px, quad -> d-octet), multiplies
// by the head's ctxn (A-operand frags loaded direct from L2-resident global),
// applies gelu, and writes G[bh][px][64e] bf16 (replaces the q intermediate).
__global__ __launch_bounds__(256) void k_qattn(
    const u16* __restrict__ fmapT, const u16* __restrict__ wq,
    const u16* __restrict__ ctxn, u16* __restrict__ G)
{
    const int t = threadIdx.x;
    const int lane = t & 63, w = t >> 6;
    const int l15 = lane & 15, quad = lane >> 4;
    const int n0 = blockIdx.x * 128;
    const int o0 = blockIdx.y * 128;
    const int b  = blockIdx.z;
    __shared__ __align__(16) unsigned char smraw[71680];
    u16* sm16 = (u16*)smraw;   // A0=0, A1=8192, B0=16384, B1=24576 (u16 offsets)
    f32x4 acc[4][4] = {};
    const int mh = (w >> 1) * 64, nh = (w & 1) * 64;
    const u16* wrow = wq + (size_t)o0 * 256;
    const u16* xrow = fmapT + ((size_t)b * NPIX + n0) * 256;
    const int srow = t >> 3;
    const int sg = t & 7;
    uint4 ra[4], rb[4];

#define Q_STAGE_LOAD(kcv)                                                              \
    {                                                                                  \
        _Pragma("unroll")                                                              \
        for (int p = 0; p < 4; ++p) {                                                  \
            int row = srow + 32 * p;                                                   \
            ra[p] = *(const uint4*)(wrow + (size_t)row * 256 + (kcv) * 64 + sg * 8);   \
            rb[p] = *(const uint4*)(xrow + (size_t)row * 256 + (kcv) * 64 + sg * 8);   \
        }                                                                              \
    }

#define Q_STAGE_WRITE(bufi)                                                            \
    {                                                                                  \
        u16* Ad = sm16 + (bufi) * 8192;                                                \
        u16* Bd = sm16 + 16384 + (bufi) * 8192;                                        \
        _Pragma("unroll")                                                              \
        for (int p = 0; p < 4; ++p) {                                                  \
            int row = srow + 32 * p;                                                   \
            int off = row * 64 + ((sg ^ (row & 7)) << 3);                              \
            *(uint4*)(Ad + off) = ra[p];                                               \
            *(uint4*)(Bd + off) = rb[p];                                               \
        }                                                                              \
    }

    Q_STAGE_LOAD(0);
    Q_STAGE_WRITE(0);
    __syncthreads();
    #pragma unroll
    for (int kc = 0; kc < 4; ++kc) {
        if (kc < 3) Q_STAGE_LOAD(kc + 1);
        {
            const u16* Ax = sm16 + (kc & 1) * 8192;
            const u16* Bx = sm16 + 16384 + (kc & 1) * 8192;
            #pragma unroll
            for (int kk = 0; kk < 64; kk += 32) {
                bf16x8 av[4], bv[4];
                #pragma unroll
                for (int mf = 0; mf < 4; ++mf) {
                    int arow = mh + mf * 16 + l15;
                    int agr = ((kk >> 3) + quad) ^ (arow & 7);
                    av[mf] = *(const bf16x8*)(Ax + arow * 64 + (agr << 3));
                }
                #pragma unroll
                for (int nf = 0; nf < 4; ++nf) {
                    int brow = nh + nf * 16 + l15;
                    int bgr = ((kk >> 3) + quad) ^ (brow & 7);
                    bv[nf] = *(const bf16x8*)(Bx + brow * 64 + (bgr << 3));
                }
                #pragma unroll
                for (int mf = 0; mf < 4; ++mf)
                    #pragma unroll
                    for (int nf = 0; nf < 4; ++nf)
                        acc[mf][nf] = __builtin_amdgcn_mfma_f32_16x16x32_bf16(av[mf], bv[nf], acc[mf][nf], 0, 0, 0);
            }
        }
        if (kc < 3) {
            Q_STAGE_WRITE((kc + 1) & 1);
            __syncthreads();
        }
    }
    __syncthreads();
    float* ep = (float*)smraw;  // [128 pix][140] fp32 logits, transposed
    #pragma unroll
    for (int mf = 0; mf < 4; ++mf)
        #pragma unroll
        for (int nf = 0; nf < 4; ++nf)
            #pragma unroll
            for (int r = 0; r < 4; ++r) {
                int row = mh + mf * 16 + quad * 4 + r;  // local channel 0..127
                int col = nh + nf * 16 + l15;           // pixel
                ep[col * 140 + row] = acc[mf][nf][r];
            }
    __syncthreads();

    // ---- softmax (per px, over the head's 64 dims) into register P frags ----
    const int hh = w >> 1;              // head within the block's 2
    const int pxh = (w & 1) * 64;       // px half owned by this wave
    const int bh = b * 8 + blockIdx.y * 2 + hh;
    const u16* cb = ctxn + (size_t)bh * 64 * 64;
    u16* Gb = G + ((size_t)bh * NPIX + n0) * 64;

    bf16x8 pa[4][2];
    #pragma unroll
    for (int mf = 0; mf < 4; ++mf) {
        int px = pxh + mf * 16 + l15;
        const float* src = ep + px * 140 + hh * 64 + quad * 8;
        f32x4 u0 = *(const f32x4*)(src);
        f32x4 u1 = *(const f32x4*)(src + 4);
        f32x4 u2 = *(const f32x4*)(src + 32);
        f32x4 u3 = *(const f32x4*)(src + 36);
        float x0 = __expf(u0[0]), x1 = __expf(u0[1]), x2 = __expf(u0[2]), x3 = __expf(u0[3]);
        float x4 = __expf(u1[0]), x5 = __expf(u1[1]), x6 = __expf(u1[2]), x7 = __expf(u1[3]);
        float y0 = __expf(u2[0]), y1 = __expf(u2[1]), y2 = __expf(u2[2]), y3 = __expf(u2[3]);
        float y4 = __expf(u3[0]), y5 = __expf(u3[1]), y6 = __expf(u3[2]), y7 = __expf(u3[3]);
        float s8 = (((x0 + x1) + (x2 + x3)) + ((x4 + x5) + (x6 + x7)))
                 + (((y0 + y1) + (y2 + y3)) + ((y4 + y5) + (y6 + y7)));
        s8 += __shfl_xor(s8, 16);
        s8 += __shfl_xor(s8, 32);
        float rs = 0.125f / s8;
        union { u32 uw[4]; bf16x8 v; } pka, pkb;
        pka.uw[0] = pk2(x0 * rs, x1 * rs); pka.uw[1] = pk2(x2 * rs, x3 * rs);
        pka.uw[2] = pk2(x4 * rs, x5 * rs); pka.uw[3] = pk2(x6 * rs, x7 * rs);
        pkb.uw[0] = pk2(y0 * rs, y1 * rs); pkb.uw[1] = pk2(y2 * rs, y3 * rs);
        pkb.uw[2] = pk2(y4 * rs, y5 * rs); pkb.uw[3] = pk2(y6 * rs, y7 * rs);
        pa[mf][0] = pka.v;
        pa[mf][1] = pkb.v;
    }

    // ---- attn: D[e][px] = sum_d ctxn[e][d] * P[px][d]  (K=64) ----
    f32x4 a2[4][4] = {};
    #pragma unroll
    for (int j = 0; j < 2; ++j) {
        bf16x8 cav[4];
        #pragma unroll
        for (int mfE = 0; mfE < 4; ++mfE)
            cav[mfE] = *(const bf16x8*)(cb + (size_t)(mfE * 16 + l15) * 64 + j * 32 + quad * 8);
        #pragma unroll
        for (int mfE = 0; mfE < 4; ++mfE)
            #pragma unroll
            for (int nfP = 0; nfP < 4; ++nfP)
                a2[mfE][nfP] = __builtin_amdgcn_mfma_f32_16x16x32_bf16(cav[mfE], pa[nfP][j], a2[mfE][nfP], 0, 0, 0);
    }

    // ---- gelu -> G[bh][px][64e], 4 consecutive e per 8B store ----
    #pragma unroll
    for (int nfP = 0; nfP < 4; ++nfP) {
        int px = pxh + nfP * 16 + l15;
        u16* gp = Gb + (size_t)px * 64;
        #pragma unroll
        for (int mfE = 0; mfE < 4; ++mfE) {
            int e0 = mfE * 16 + quad * 4;
            float g0 = a2[mfE][nfP][0], g1 = a2[mfE][nfP][1];
            float g2 = a2[mfE][nfP][2], g3 = a2[mfE][nfP][3];
            g0 = 0.5f * g0 * (1.0f + erff(g0 * 0.70710678118654752f));
            g1 = 0.5f * g1 * (1.0f + erff(g1 * 0.70710678118654752f));
            g2 = 0.5f * g2 * (1.0f + erff(g2 * 0.70710678118654752f));
            g3 = 0.5f * g3 * (1.0f + erff(g3 * 0.70710678118654752f));
            uint2 u; u.x = pk2(g0, g1); u.y = pk2(g2, g3);
            *(uint2*)(gp + e0) = u;
        }
    }
#undef Q_STAGE_LOAD
#undef Q_STAGE_WRITE
}

// ---------------- K4: pure GEMM out[ch][px] = wout[ch][:] @ G[:][px] + b ----------------
// No LDS, no barriers. A = G px-rows (D rows = px -> 16B f32x4 stores),
// B = wout ch-rows (L2-resident). Wave owns [128px][64ch]; acc 8x4 f32x4.
__global__ __launch_bounds__(256) void k_out(
    const u16* __restrict__ G, const u16* __restrict__ wout,
    const float* __restrict__ bout, float* __restrict__ out)
{
    const int t = threadIdx.x;
    const int lane = t & 63, w = t >> 6;
    const int l15 = lane & 15, quad = lane >> 4;
    const int n0 = blockIdx.x * 128;
    const int b  = blockIdx.y;

    f32x4 acc[8][4] = {};
    for (int h = 0; h < 8; ++h) {
        const u16* Gh = G + (((size_t)(b * 8 + h)) * NPIX + n0) * 64;
        #pragma unroll
        for (int j = 0; j < 2; ++j) {
            bf16x8 av[8], bv[4];
            #pragma unroll
            for (int mfP = 0; mfP < 8; ++mfP)
                av[mfP] = *(const bf16x8*)(Gh + (size_t)(mfP * 16 + l15) * 64 + j * 32 + quad * 8);
            #pragma unroll
            for (int nfC = 0; nfC < 4; ++nfC)
                bv[nfC] = *(const bf16x8*)(wout + (size_t)(w * 64 + nfC * 16 + l15) * 512 + h * 64 + j * 32 + quad * 8);
            #pragma unroll
            for (int mfP = 0; mfP < 8; ++mfP)
                #pragma unroll
                for (int nfC = 0; nfC < 4; ++nfC)
                    acc[mfP][nfC] = __builtin_amdgcn_mfma_f32_16x16x32_bf16(av[mfP], bv[nfC], acc[mfP][nfC], 0, 0, 0);
        }
    }
    #pragma unroll
    for (int nfC = 0; nfC < 4; ++nfC) {
        int ch = w * 64 + nfC * 16 + l15;
        float bb = bout[ch];
        float* orow = out + ((size_t)b * 256 + ch) * NPIX + n0;
        #pragma unroll
        for (int mfP = 0; mfP < 8; ++mfP) {
            int px0 = mfP * 16 + quad * 4;
            f32x4 v = acc[mfP][nfC];
            v[0] += bb; v[1] += bb; v[2] += bb; v[3] += bb;
            *(f32x4*)(orow + px0) = v;
        }
    }
}

extern "C" void kernel_launch(void* const* d_in, const int* in_sizes, int n_in,
                              void* d_out, int out_size, void* d_ws, size_t ws_size,
                              hipStream_t stream)
{
    const float* fmap  = (const float*)d_in[0];
    const float* w_q   = (const float*)d_in[1];
    const float* w_dw  = (const float*)d_in[2];
    const float* w_pw  = (const float*)d_in[3];
    const float* w_out = (const float*)d_in[4];
    const float* b_out = (const float*)d_in[5];
    float* out = (float*)d_out;
    char* ws = (char*)d_ws;

    u16* dwT     = (u16*)(ws);                  // 67,108,864 B  [8][16384][256] (dead after k_kvctx)
    u16* ctxn    = (u16*)(ws);                  // 524,288 B — reuses dwT region post-k_kvctx
    u16* fmapT   = (u16*)(ws + 67108864);       // 67,108,864 B
    u16* G       = (u16*)(ws + 134217728);      // 134,217,728 B [8b][8h][16384px][64e] bf16
    float* ctx   = (float*)(ws + 402653184);    // 1,048,576 B  [64][64][64]
    float* denom = (float*)(ws + 403701760);    // 16,384 B
    u16* wq_b    = (u16*)(ws + 403718144);      // 262,144 B
    u16* wpw_b   = (u16*)(ws + 403980288);      // 524,288 B
    u16* wout_b  = (u16*)(ws + 404504576);      // 262,144 B
    // total workspace: 404,766,720 B

    hipMemsetAsync(ws + 402653184, 0, 1048576 + 16384, stream);
    k_cvtw<<<512, 256, 0, stream>>>(w_q, w_pw, w_out, wq_b, wpw_b, wout_b);
    k_conv<<<dim3(128, 8), 256, 0, stream>>>(fmap, w_dw, fmapT, dwT);
    k_kvctx<<<1024, 256, 0, stream>>>(dwT, wpw_b, ctx, denom);
    k_ctxn<<<64, 256, 0, stream>>>(ctx, denom, ctxn);   // after k_kvctx; overwrites dwT region
    k_qattn<<<dim3(128, 4, 8), 256, 0, stream>>>(fmapT, wq_b, ctxn, G);
    k_out<<<dim3(128, 8), 256, 0, stream>>>(G, wout_b, b_out, out);
}